// Round 1
// baseline (6430.704 us; speedup 1.0000x reference)
//
#include <hip/hip_runtime.h>
#include <math.h>

// Problem constants
constexpr int B  = 128;
constexpr int T  = 512;
constexpr int IN = 32;
constexpr int H  = 256;
constexpr int G3 = 3 * H;     // 768
constexpr int D  = 2 * H;     // 512
constexpr int NC = 1024;      // codebook entries

// ---------------------------------------------------------------------------
// prep kernels
// ---------------------------------------------------------------------------

__global__ void k_zero(int* __restrict__ counts, double* __restrict__ lsum) {
    const int t = threadIdx.x;
    if (t < NC) counts[t] = 0;
    if (t == 0) *lsum = 0.0;
}

// lengths: last[b] = (# ones in mask row) - 1   (mask is a contiguous prefix)
__global__ void k_lengths(const int* __restrict__ mask, int* __restrict__ last) {
    const int b = blockIdx.x;
    const int t = threadIdx.x;   // 64 threads = 1 wave
    int s = 0;
    #pragma unroll
    for (int m = 0; m < T / 64; ++m) s += mask[b * T + m * 64 + t];
    #pragma unroll
    for (int off = 32; off > 0; off >>= 1) s += __shfl_down(s, off, 64);
    if (t == 0) last[b] = s - 1;
}

// rank-sort batches by length so paired batches have similar lengths
__global__ void k_sort(const int* __restrict__ last, int* __restrict__ order) {
    __shared__ int ll[B];
    const int t = threadIdx.x;   // 128 threads
    ll[t] = last[t];
    __syncthreads();
    const int mine = ll[t];
    int r = 0;
    for (int j = 0; j < B; ++j) {
        const int lj = ll[j];
        r += (lj < mine) || (lj == mine && j < t);
    }
    order[r] = t;
}

// generic transpose: src[rows][cols] -> dst[cols][rows]; writes coalesced
__global__ void k_transpose(float* __restrict__ dst, const float* __restrict__ src,
                            int rows, int cols) {
    const int idx = blockIdx.x * 256 + threadIdx.x;
    const int r = idx % rows;
    const int c = idx / rows;
    dst[idx] = src[r * cols + c];
}

// codebook squared norms in fp64
__global__ void k_cbn2(const float* __restrict__ cb, double* __restrict__ cbn2) {
    const int c = blockIdx.x * 256 + threadIdx.x;   // 4 blocks x 256 = 1024
    double s = 0.0;
    for (int k = 0; k < D; ++k) {
        const double e = (double)cb[c * D + k];
        s += e * e;
    }
    cbn2[c] = s;
}

// ---------------------------------------------------------------------------
// GRU: one WG per pair of (length-sorted) batches; forward phase then backward
// phase. Weights streamed from L2 (K-major layout, coalesced dword loads).
// fp32 math throughout to track the jax fp32 reference.
// ---------------------------------------------------------------------------

__device__ __forceinline__ float sigmoidf_(float x) {
    return 1.0f / (1.0f + expf(-x));
}

__global__ __launch_bounds__(256, 1) void k_gru(
    const float* __restrict__ traj,
    const float* __restrict__ WhTf, const float* __restrict__ WhTb,
    const float* __restrict__ WxTf, const float* __restrict__ WxTb,
    const float* __restrict__ bxf, const float* __restrict__ bhf,
    const float* __restrict__ bxb, const float* __restrict__ bhb,
    const int* __restrict__ last, const int* __restrict__ order,
    float* __restrict__ ze)
{
    __shared__ float2 lh[2][H];    // ping-pong h state, (batch0, batch1) interleaved
    __shared__ float2 lx[2][IN];   // ping-pong x_t

    const int j = threadIdx.x;     // 256 threads <-> 256 h dims
    const int g = blockIdx.x;      // 64 groups
    const int b0 = order[2 * g];
    const int b1 = order[2 * g + 1];
    const int l0 = last[b0];
    const int l1 = last[b1];

    for (int dphase = 0; dphase < 2; ++dphase) {
        const float* __restrict__ WhT = dphase ? WhTb : WhTf;
        const float* __restrict__ WxT = dphase ? WxTb : WxTf;
        const float* __restrict__ bx  = dphase ? bxb : bxf;
        const float* __restrict__ bh  = dphase ? bhb : bhf;

        const float bxr = bx[j], bxz = bx[j + H], bxn = bx[j + 2 * H];
        const float bhr = bh[j], bhz = bh[j + H], bhn = bh[j + 2 * H];

        int t0, t_end, dt;
        if (dphase == 0) { t0 = 0;     t_end = (l0 > l1 ? l0 : l1); dt = 1;  }
        else             { t0 = T - 1; t_end = (l0 < l1 ? l0 : l1); dt = -1; }

        int cur = 0;
        lh[0][j] = make_float2(0.0f, 0.0f);
        if (j < 64) {
            const int c = j >> 5, i = j & 31;
            const int bb = c ? b1 : b0;
            float* p = (float*)&lx[0][i];
            p[c] = traj[(bb * T + t0) * IN + i];
        }
        __syncthreads();

        for (int t = t0; dphase ? (t >= t_end) : (t <= t_end); t += dt) {
            float ahr0 = bhr, ahz0 = bhz, ahn0 = bhn;
            float ahr1 = bhr, ahz1 = bhz, ahn1 = bhn;
            const float2* __restrict__ hp = lh[cur];
            const float*  __restrict__ wp = WhT + j;
            #pragma unroll 8
            for (int k = 0; k < H; ++k) {
                const float wr = wp[k * G3];
                const float wz = wp[k * G3 + H];
                const float wn = wp[k * G3 + 2 * H];
                const float2 hv = hp[k];
                ahr0 = fmaf(wr, hv.x, ahr0); ahr1 = fmaf(wr, hv.y, ahr1);
                ahz0 = fmaf(wz, hv.x, ahz0); ahz1 = fmaf(wz, hv.y, ahz1);
                ahn0 = fmaf(wn, hv.x, ahn0); ahn1 = fmaf(wn, hv.y, ahn1);
            }
            float axr0 = bxr, axz0 = bxz, axn0 = bxn;
            float axr1 = bxr, axz1 = bxz, axn1 = bxn;
            const float2* __restrict__ xpd = lx[cur];
            const float*  __restrict__ xp  = WxT + j;
            #pragma unroll
            for (int i = 0; i < IN; ++i) {
                const float wr = xp[i * G3];
                const float wz = xp[i * G3 + H];
                const float wn = xp[i * G3 + 2 * H];
                const float2 xv = xpd[i];
                axr0 = fmaf(wr, xv.x, axr0); axr1 = fmaf(wr, xv.y, axr1);
                axz0 = fmaf(wz, xv.x, axz0); axz1 = fmaf(wz, xv.y, axz1);
                axn0 = fmaf(wn, xv.x, axn0); axn1 = fmaf(wn, xv.y, axn1);
            }
            const float2 hprev = lh[cur][j];

            const float r0 = sigmoidf_(axr0 + ahr0);
            const float z0 = sigmoidf_(axz0 + ahz0);
            const float n0 = tanhf(axn0 + r0 * ahn0);
            const float hn0 = (1.0f - z0) * n0 + z0 * hprev.x;

            const float r1 = sigmoidf_(axr1 + ahr1);
            const float z1 = sigmoidf_(axz1 + ahz1);
            const float n1 = tanhf(axn1 + r1 * ahn1);
            const float hn1 = (1.0f - z1) * n1 + z1 * hprev.y;

            const int nxt = cur ^ 1;
            lh[nxt][j] = make_float2(hn0, hn1);

            if (t == l0) ze[b0 * D + dphase * H + j] = hn0;
            if (t == l1) ze[b1 * D + dphase * H + j] = hn1;

            const int tn = t + dt;
            const bool more = dphase ? (tn >= t_end) : (tn <= t_end);
            if (more && j < 64) {
                const int c = j >> 5, i = j & 31;
                const int bb = c ? b1 : b0;
                float* p = (float*)&lx[nxt][i];
                p[c] = traj[(bb * T + tn) * IN + i];
            }
            __syncthreads();
            cur = nxt;
        }
        __syncthreads();
    }
}

// ---------------------------------------------------------------------------
// VQ: fp64 distance accumulation to match the numpy (fp64) argmin ordering.
// One WG per batch row. d = |e|^2 - 2 z.e   (|z|^2 constant per row, dropped)
// ---------------------------------------------------------------------------

__global__ __launch_bounds__(256) void k_vq(
    const float* __restrict__ ze, const float* __restrict__ cbT,
    const float* __restrict__ cb, const double* __restrict__ cbn2,
    int* __restrict__ counts, double* __restrict__ lsum,
    float* __restrict__ out)
{
    __shared__ float lz[D];
    __shared__ double ds[256];
    __shared__ int cs[256];

    const int b = blockIdx.x;
    const int t = threadIdx.x;

    lz[t]       = ze[b * D + t];
    lz[t + 256] = ze[b * D + 256 + t];
    __syncthreads();

    double best = 1e300;
    int bc = 0;
    for (int m = 0; m < NC / 256; ++m) {
        const int c = m * 256 + t;
        double s2 = 0.0;
        #pragma unroll 4
        for (int k = 0; k < D; ++k)
            s2 += (double)lz[k] * (double)cbT[k * NC + c];
        const double dist = cbn2[c] - 2.0 * s2;
        if (dist < best) { best = dist; bc = c; }   // m ascending -> first index kept
    }
    ds[t] = best; cs[t] = bc;
    __syncthreads();
    for (int s = 128; s > 0; s >>= 1) {
        if (t < s) {
            if (ds[t + s] < ds[t] || (ds[t + s] == ds[t] && cs[t + s] < cs[t])) {
                ds[t] = ds[t + s]; cs[t] = cs[t + s];
            }
        }
        __syncthreads();
    }
    const int idx = cs[0];
    __syncthreads();

    if (t == 0) atomicAdd(&counts[idx], 1);

    double loc = 0.0;
    for (int jj = t; jj < D; jj += 256) {
        const float zev = lz[jj];
        const float zqv = cb[idx * D + jj];
        out[b * D + jj] = zev + (zqv - zev);        // straight-through, mimic ref
        const double df = (double)zqv - (double)zev;
        loc += df * df;
    }
    ds[t] = loc;
    __syncthreads();
    for (int s = 128; s > 0; s >>= 1) {
        if (t < s) ds[t] += ds[t + s];
        __syncthreads();
    }
    if (t == 0) atomicAdd(lsum, ds[0]);
}

__global__ void k_final(const int* __restrict__ counts,
                        const double* __restrict__ lsum,
                        float* __restrict__ out)
{
    __shared__ double ds[256];
    const int t = threadIdx.x;
    double s = 0.0;
    for (int c = t; c < NC; c += 256) {
        const double p = (double)counts[c] / (double)B;
        s += p * log(p + 1e-10);
    }
    ds[t] = s;
    __syncthreads();
    for (int r = 128; r > 0; r >>= 1) {
        if (t < r) ds[t] += ds[t + r];
        __syncthreads();
    }
    if (t == 0) {
        out[B * D]     = (float)(lsum[0] * 1.25 / (double)(B * D));  // (1+beta)*mean
        out[B * D + 1] = (float)exp(-ds[0]);
    }
}

// ---------------------------------------------------------------------------
// launch
// ---------------------------------------------------------------------------

extern "C" void kernel_launch(void* const* d_in, const int* in_sizes, int n_in,
                              void* d_out, int out_size, void* d_ws, size_t ws_size,
                              hipStream_t stream) {
    const float* traj = (const float*)d_in[0];
    const int*   mask = (const int*)d_in[1];
    const float* Wxf  = (const float*)d_in[2];
    const float* Whf  = (const float*)d_in[3];
    const float* bxf  = (const float*)d_in[4];
    const float* bhf  = (const float*)d_in[5];
    const float* Wxb  = (const float*)d_in[6];
    const float* Whb  = (const float*)d_in[7];
    const float* bxb  = (const float*)d_in[8];
    const float* bhb  = (const float*)d_in[9];
    const float* cb   = (const float*)d_in[10];
    float* out = (float*)d_out;

    // workspace layout (floats), all fp64 slots 8B-aligned
    float* ws    = (float*)d_ws;
    float* WhTf  = ws;                   // 256*768 = 196608
    float* WhTb  = WhTf + 196608;        // 196608
    float* WxTf  = WhTb + 196608;        // 32*768 = 24576
    float* WxTb  = WxTf + 24576;         // 24576
    float* cbT   = WxTb + 24576;         // 512*1024 = 524288
    float* zebuf = cbT + 524288;         // 128*512 = 65536
    int*   last  = (int*)(zebuf + 65536);// 128
    int*   order = last + 128;           // 128
    int*   cnts  = order + 128;          // 1024
    double* cbn2 = (double*)(cnts + 1024); // 1024 doubles
    double* lsum = cbn2 + 1024;          // 1 double

    k_zero<<<dim3(1), dim3(1024), 0, stream>>>(cnts, lsum);
    k_lengths<<<dim3(B), dim3(64), 0, stream>>>(mask, last);
    k_sort<<<dim3(1), dim3(B), 0, stream>>>(last, order);

    k_transpose<<<dim3(768),  dim3(256), 0, stream>>>(WhTf, Whf, G3, H);
    k_transpose<<<dim3(768),  dim3(256), 0, stream>>>(WhTb, Whb, G3, H);
    k_transpose<<<dim3(96),   dim3(256), 0, stream>>>(WxTf, Wxf, G3, IN);
    k_transpose<<<dim3(96),   dim3(256), 0, stream>>>(WxTb, Wxb, G3, IN);
    k_transpose<<<dim3(2048), dim3(256), 0, stream>>>(cbT, cb, NC, D);
    k_cbn2<<<dim3(4), dim3(256), 0, stream>>>(cb, cbn2);

    k_gru<<<dim3(B / 2), dim3(256), 0, stream>>>(traj, WhTf, WhTb, WxTf, WxTb,
                                                 bxf, bhf, bxb, bhb,
                                                 last, order, zebuf);

    k_vq<<<dim3(B), dim3(256), 0, stream>>>(zebuf, cbT, cb, cbn2, cnts, lsum, out);
    k_final<<<dim3(1), dim3(256), 0, stream>>>(cnts, lsum, out);
}

// Round 2
// 4141.460 us; speedup vs baseline: 1.5528x; 1.5528x over previous
//
#include <hip/hip_runtime.h>
#include <math.h>

// Problem constants
constexpr int B  = 128;
constexpr int T  = 512;
constexpr int IN = 32;
constexpr int H  = 256;
constexpr int D  = 2 * H;     // 512
constexpr int NC = 1024;      // codebook entries

// cooperative GRU geometry
constexpr int NG   = 64;      // groups (32 fwd + 32 bwd)
constexpr int GW   = 4;       // WGs per group
constexpr int SEQ  = 4;       // sequences per group
constexpr int ROWS = 192;     // gate-rows per WG (3 gates x 64 j)
constexpr int NTHR = 768;     // ROWS x 4 k-chunks

// ---------------------------------------------------------------------------
// prep kernels
// ---------------------------------------------------------------------------

__global__ void k_zero(int* __restrict__ flags, int* __restrict__ counts,
                       double* __restrict__ lsum) {
    const int i = blockIdx.x * 256 + threadIdx.x;   // grid 16 x 256 = 4096
    if (i < 4096) flags[i] = 0;
    if (i < NC) counts[i] = 0;
    if (i == 0) *lsum = 0.0;
}

__global__ void k_lengths(const int* __restrict__ mask, int* __restrict__ last) {
    const int b = blockIdx.x;
    const int t = threadIdx.x;   // 64 threads = 1 wave
    int s = 0;
    #pragma unroll
    for (int m = 0; m < T / 64; ++m) s += mask[b * T + m * 64 + t];
    #pragma unroll
    for (int off = 32; off > 0; off >>= 1) s += __shfl_down(s, off, 64);
    if (t == 0) last[b] = s - 1;
}

// build direction-pure, length-sorted groups of 4 tasks
__global__ void k_plan(const int* __restrict__ last, int* __restrict__ plan,
                       int* __restrict__ slen, int* __restrict__ glen) {
    __shared__ int ll[B];
    const int t = threadIdx.x;   // 128
    ll[t] = last[t];
    __syncthreads();
    const int lf = ll[t] + 1;       // fwd steps
    const int lb = T - ll[t];       // bwd steps
    int rf = 0, rb = 0;
    for (int j = 0; j < B; ++j) {
        const int ljf = ll[j] + 1, ljb = T - ll[j];
        rf += (ljf > lf) || (ljf == lf && j < t);   // descending
        rb += (ljb > lb) || (ljb == lb && j < t);
    }
    plan[rf] = t;       slen[rf] = lf;
    plan[128 + rb] = t; slen[128 + rb] = lb;
    if ((rf & 3) == 0) glen[rf >> 2] = lf;          // rank 4g = group max
    if ((rb & 3) == 0) glen[32 + (rb >> 2)] = lb;
}

// transpose codebook for k_vq
__global__ void k_transpose(float* __restrict__ dst, const float* __restrict__ src,
                            int rows, int cols) {
    const int idx = blockIdx.x * 256 + threadIdx.x;
    const int r = idx % rows;
    const int c = idx / rows;
    dst[idx] = src[r * cols + c];
}

__global__ void k_cbn2(const float* __restrict__ cb, double* __restrict__ cbn2) {
    const int c = blockIdx.x * 256 + threadIdx.x;
    double s = 0.0;
    for (int k = 0; k < D; ++k) {
        const double e = (double)cb[c * D + k];
        s += e * e;
    }
    cbn2[c] = s;
}

// ---------------------------------------------------------------------------
// Cooperative GRU: weights live in VGPRs; 4 WGs per group exchange h slices
// through global memory with step-numbered device-scope flags.
// grid = 256 WGs (1/CU, all resident), 768 threads each.
// ---------------------------------------------------------------------------

__device__ __forceinline__ float sigmoidf_(float x) {
    return 1.0f / (1.0f + expf(-x));
}

__global__ __launch_bounds__(NTHR, 3) void k_gru(
    const float* __restrict__ traj,
    const float* __restrict__ Whf, const float* __restrict__ Whb,
    const float* __restrict__ Wxf, const float* __restrict__ Wxb,
    const float* __restrict__ bxf, const float* __restrict__ bhf,
    const float* __restrict__ bxb, const float* __restrict__ bhb,
    const int* __restrict__ plan, const int* __restrict__ slen,
    const int* __restrict__ glen,
    float* __restrict__ hg,        // [2][NG][SEQ][256]
    int* __restrict__ flags,       // [NG][GW*16]
    float* __restrict__ ze)        // [B][512]
{
    const int g   = blockIdx.x & 63;     // same-XCD members under %8 round-robin
    const int w   = blockIdx.x >> 6;
    const int dir = (g >= 32) ? 1 : 0;

    const float* __restrict__ Wh = dir ? Whb : Whf;
    const float* __restrict__ Wx = dir ? Wxb : Wxf;
    const float* __restrict__ bx = dir ? bxb : bxf;
    const float* __restrict__ bh = dir ? bhb : bhf;

    const int tid = threadIdx.x;
    const int q   = tid / ROWS;          // k-chunk 0..3 (wave-uniform)
    const int lr  = tid % ROWS;          // local row 0..191
    const int gi  = lr >> 6;             // gate 0=r,1=z,2=n
    const int jj  = lr & 63;
    const int R   = gi * H + w * 64 + jj;   // global gate-row

    __shared__ float4 h4[SEQ][64];            // full h per sequence (4 KB)
    __shared__ float  Ph[ROWS * 17];          // h-dot partials [row][s*4+q]
    __shared__ float  Px[ROWS * 17];          // x-dot partials
    __shared__ float4 xb4[2][SEQ][8];         // x_t ping-pong
    __shared__ float  lbh[ROWS], lbx[ROWS];
    __shared__ int    bbS[SEQ], lsS[SEQ];

    if (tid < SEQ) { bbS[tid] = plan[g * 4 + tid]; lsS[tid] = slen[g * 4 + tid]; }
    {   // zero h
        float2* hp = (float2*)h4;
        if (tid < 512) hp[tid] = make_float2(0.0f, 0.0f);
    }
    const int L = glen[g];

    // load Wh slice into registers (one-time)
    float4 wh[16];
    {
        const float4* p = (const float4*)(Wh + R * 256 + q * 64);
        #pragma unroll
        for (int i = 0; i < 16; ++i) wh[i] = p[i];
    }
    float4 wx[2];
    {
        const float4* p = (const float4*)(Wx + R * 32 + q * 8);
        wx[0] = p[0]; wx[1] = p[1];
    }
    if (tid < ROWS) { lbh[tid] = bh[R]; lbx[tid] = bx[R]; }
    __syncthreads();
    // x for step 1
    if (tid < 128) {
        const int s = tid >> 5, i = tid & 31;
        const int t0 = dir ? (T - 1) : 0;
        ((float*)xb4)[128 + s * 32 + i] = traj[(bbS[s] * T + t0) * IN + i];
    }
    __syncthreads();

    for (int step = 1; step <= L; ++step) {
        const int buf = step & 1;
        // ---- phase 1: partial dot products (weights in VGPRs) ----
        float a0 = 0.f, a1 = 0.f, a2 = 0.f, a3 = 0.f;
        #pragma unroll
        for (int i = 0; i < 16; ++i) {
            const float4 wv = wh[i];
            float4 hv;
            hv = h4[0][q * 16 + i];
            a0 = fmaf(wv.x, hv.x, fmaf(wv.y, hv.y, fmaf(wv.z, hv.z, fmaf(wv.w, hv.w, a0))));
            hv = h4[1][q * 16 + i];
            a1 = fmaf(wv.x, hv.x, fmaf(wv.y, hv.y, fmaf(wv.z, hv.z, fmaf(wv.w, hv.w, a1))));
            hv = h4[2][q * 16 + i];
            a2 = fmaf(wv.x, hv.x, fmaf(wv.y, hv.y, fmaf(wv.z, hv.z, fmaf(wv.w, hv.w, a2))));
            hv = h4[3][q * 16 + i];
            a3 = fmaf(wv.x, hv.x, fmaf(wv.y, hv.y, fmaf(wv.z, hv.z, fmaf(wv.w, hv.w, a3))));
        }
        float b0 = 0.f, b1 = 0.f, b2 = 0.f, b3 = 0.f;
        #pragma unroll
        for (int i = 0; i < 2; ++i) {
            const float4 wv = wx[i];
            float4 xv;
            xv = xb4[buf][0][q * 2 + i];
            b0 = fmaf(wv.x, xv.x, fmaf(wv.y, xv.y, fmaf(wv.z, xv.z, fmaf(wv.w, xv.w, b0))));
            xv = xb4[buf][1][q * 2 + i];
            b1 = fmaf(wv.x, xv.x, fmaf(wv.y, xv.y, fmaf(wv.z, xv.z, fmaf(wv.w, xv.w, b1))));
            xv = xb4[buf][2][q * 2 + i];
            b2 = fmaf(wv.x, xv.x, fmaf(wv.y, xv.y, fmaf(wv.z, xv.z, fmaf(wv.w, xv.w, b2))));
            xv = xb4[buf][3][q * 2 + i];
            b3 = fmaf(wv.x, xv.x, fmaf(wv.y, xv.y, fmaf(wv.z, xv.z, fmaf(wv.w, xv.w, b3))));
        }
        {
            const int o = lr * 17 + q;
            Ph[o]      = a0; Ph[o + 4]  = a1; Ph[o + 8]  = a2; Ph[o + 12] = a3;
            Px[o]      = b0; Px[o + 4]  = b1; Px[o + 8]  = b2; Px[o + 12] = b3;
        }
        __syncthreads();

        // ---- phase 2: combine gates (256 thr) + x prefetch (128 thr) ----
        if (tid < 256) {
            const int j2 = tid & 63, s = tid >> 6;
            const int c = s * 4;
            float hr = 0.f, hz = 0.f, hn_ = 0.f, xr = 0.f, xz = 0.f, xn = 0.f;
            #pragma unroll
            for (int q2 = 0; q2 < 4; ++q2) {
                hr  += Ph[j2 * 17 + c + q2];
                hz  += Ph[(64 + j2) * 17 + c + q2];
                hn_ += Ph[(128 + j2) * 17 + c + q2];
                xr  += Px[j2 * 17 + c + q2];
                xz  += Px[(64 + j2) * 17 + c + q2];
                xn  += Px[(128 + j2) * 17 + c + q2];
            }
            const float r = sigmoidf_(xr + lbx[j2] + hr + lbh[j2]);
            const float z = sigmoidf_(xz + lbx[64 + j2] + hz + lbh[64 + j2]);
            const float n = tanhf(xn + lbx[128 + j2] + r * (hn_ + lbh[128 + j2]));
            const int jg = w * 64 + j2;
            const float hp = ((const float*)h4)[s * 256 + jg];
            const float hnew = (1.0f - z) * n + z * hp;
            hg[buf * (NG * SEQ * 256) + g * (SEQ * 256) + s * 256 + jg] = hnew;
            if (step == lsS[s]) ze[bbS[s] * D + dir * H + jg] = hnew;
        } else if (tid < 384) {
            if (step < L) {
                const int u = tid - 256;
                const int s = u >> 5, i = u & 31;
                const int tn = dir ? (T - 1 - step) : step;
                ((float*)xb4)[(buf ^ 1) * 128 + s * 32 + i] =
                    traj[(bbS[s] * T + tn) * IN + i];
            }
        }
        __syncthreads();   // drains vmem: hg writes complete to L2

        // ---- inter-WG sync (device scope, double-buffered, step-numbered) ----
        if (tid == 0) {
            __threadfence();
            __hip_atomic_store(&flags[g * 64 + w * 16], step,
                               __ATOMIC_RELEASE, __HIP_MEMORY_SCOPE_AGENT);
        }
        if (tid < GW) {
            while (__hip_atomic_load(&flags[g * 64 + tid * 16],
                                     __ATOMIC_ACQUIRE, __HIP_MEMORY_SCOPE_AGENT) < step) {
                __builtin_amdgcn_s_sleep(1);
            }
        }
        __syncthreads();

        // ---- gather full h for next step ----
        if (tid < 512) {
            const float2* src = (const float2*)(hg + buf * (NG * SEQ * 256)
                                                   + g * (SEQ * 256));
            ((float2*)h4)[tid] = src[tid];
        }
        __syncthreads();
    }
}

// ---------------------------------------------------------------------------
// VQ: fp64 distance accumulation to match the numpy (fp64) argmin ordering.
// ---------------------------------------------------------------------------

__global__ __launch_bounds__(256) void k_vq(
    const float* __restrict__ ze, const float* __restrict__ cbT,
    const float* __restrict__ cb, const double* __restrict__ cbn2,
    int* __restrict__ counts, double* __restrict__ lsum,
    float* __restrict__ out)
{
    __shared__ float lz[D];
    __shared__ double ds[256];
    __shared__ int cs[256];

    const int b = blockIdx.x;
    const int t = threadIdx.x;

    lz[t]       = ze[b * D + t];
    lz[t + 256] = ze[b * D + 256 + t];
    __syncthreads();

    double best = 1e300;
    int bc = 0;
    for (int m = 0; m < NC / 256; ++m) {
        const int c = m * 256 + t;
        double s2 = 0.0;
        #pragma unroll 4
        for (int k = 0; k < D; ++k)
            s2 += (double)lz[k] * (double)cbT[k * NC + c];
        const double dist = cbn2[c] - 2.0 * s2;
        if (dist < best) { best = dist; bc = c; }
    }
    ds[t] = best; cs[t] = bc;
    __syncthreads();
    for (int s = 128; s > 0; s >>= 1) {
        if (t < s) {
            if (ds[t + s] < ds[t] || (ds[t + s] == ds[t] && cs[t + s] < cs[t])) {
                ds[t] = ds[t + s]; cs[t] = cs[t + s];
            }
        }
        __syncthreads();
    }
    const int idx = cs[0];
    __syncthreads();

    if (t == 0) atomicAdd(&counts[idx], 1);

    double loc = 0.0;
    for (int jj = t; jj < D; jj += 256) {
        const float zev = lz[jj];
        const float zqv = cb[idx * D + jj];
        out[b * D + jj] = zev + (zqv - zev);
        const double df = (double)zqv - (double)zev;
        loc += df * df;
    }
    ds[t] = loc;
    __syncthreads();
    for (int s = 128; s > 0; s >>= 1) {
        if (t < s) ds[t] += ds[t + s];
        __syncthreads();
    }
    if (t == 0) atomicAdd(lsum, ds[0]);
}

__global__ void k_final(const int* __restrict__ counts,
                        const double* __restrict__ lsum,
                        float* __restrict__ out)
{
    __shared__ double ds[256];
    const int t = threadIdx.x;
    double s = 0.0;
    for (int c = t; c < NC; c += 256) {
        const double p = (double)counts[c] / (double)B;
        s += p * log(p + 1e-10);
    }
    ds[t] = s;
    __syncthreads();
    for (int r = 128; r > 0; r >>= 1) {
        if (t < r) ds[t] += ds[t + r];
        __syncthreads();
    }
    if (t == 0) {
        out[B * D]     = (float)(lsum[0] * 1.25 / (double)(B * D));
        out[B * D + 1] = (float)exp(-ds[0]);
    }
}

// ---------------------------------------------------------------------------
// launch
// ---------------------------------------------------------------------------

extern "C" void kernel_launch(void* const* d_in, const int* in_sizes, int n_in,
                              void* d_out, int out_size, void* d_ws, size_t ws_size,
                              hipStream_t stream) {
    const float* traj = (const float*)d_in[0];
    const int*   mask = (const int*)d_in[1];
    const float* Wxf  = (const float*)d_in[2];
    const float* Whf  = (const float*)d_in[3];
    const float* bxf  = (const float*)d_in[4];
    const float* bhf  = (const float*)d_in[5];
    const float* Wxb  = (const float*)d_in[6];
    const float* Whb  = (const float*)d_in[7];
    const float* bxb  = (const float*)d_in[8];
    const float* bhb  = (const float*)d_in[9];
    const float* cb   = (const float*)d_in[10];
    float* out = (float*)d_out;

    // workspace layout
    float* ws    = (float*)d_ws;
    float* cbT   = ws;                     // 512*1024 = 524288
    float* zebuf = cbT + 524288;           // 128*512  = 65536
    float* hg    = zebuf + 65536;          // 2*64*4*256 = 131072
    int*   last  = (int*)(hg + 131072);    // 128
    int*   plan  = last + 128;             // 256
    int*   slen  = plan + 256;             // 256
    int*   glen  = slen + 256;             // 64
    int*   flags = glen + 64;              // 64*64 = 4096
    int*   cnts  = flags + 4096;           // 1024
    double* cbn2 = (double*)(cnts + 1024); // 1024 doubles (8B aligned)
    double* lsum = cbn2 + 1024;            // 1 double

    k_zero<<<dim3(16), dim3(256), 0, stream>>>(flags, cnts, lsum);
    k_lengths<<<dim3(B), dim3(64), 0, stream>>>(mask, last);
    k_plan<<<dim3(1), dim3(B), 0, stream>>>(last, plan, slen, glen);

    k_transpose<<<dim3(2048), dim3(256), 0, stream>>>(cbT, cb, NC, D);
    k_cbn2<<<dim3(4), dim3(256), 0, stream>>>(cb, cbn2);

    k_gru<<<dim3(NG * GW), dim3(NTHR), 0, stream>>>(
        traj, Whf, Whb, Wxf, Wxb, bxf, bhf, bxb, bhb,
        plan, slen, glen, hg, flags, zebuf);

    k_vq<<<dim3(B), dim3(256), 0, stream>>>(zebuf, cbT, cb, cbn2, cnts, lsum, out);
    k_final<<<dim3(1), dim3(256), 0, stream>>>(cnts, lsum, out);
}

// Round 3
// 2372.900 us; speedup vs baseline: 2.7101x; 1.7453x over previous
//
#include <hip/hip_runtime.h>
#include <math.h>

// Problem constants
constexpr int B  = 128;
constexpr int T  = 512;
constexpr int IN = 32;
constexpr int H  = 256;
constexpr int D  = 2 * H;     // 512
constexpr int NC = 1024;      // codebook entries

// cooperative GRU geometry
constexpr int NG   = 64;      // groups (32 fwd + 32 bwd)
constexpr int GW   = 4;       // WGs per group
constexpr int SEQ  = 4;       // sequences per group
constexpr int ROWS = 192;     // gate-rows per WG (3 gates x 64 j)
constexpr int NTHR = 768;     // ROWS x 4 k-chunks

// ---------------------------------------------------------------------------
// prep kernels
// ---------------------------------------------------------------------------

__global__ void k_zero(int* __restrict__ flags, int* __restrict__ counts,
                       double* __restrict__ lsum) {
    const int i = blockIdx.x * 256 + threadIdx.x;   // grid 16 x 256 = 4096
    if (i < 4096) flags[i] = 0;
    if (i < NC) counts[i] = 0;
    if (i == 0) *lsum = 0.0;
}

__global__ void k_lengths(const int* __restrict__ mask, int* __restrict__ last) {
    const int b = blockIdx.x;
    const int t = threadIdx.x;   // 64 threads = 1 wave
    int s = 0;
    #pragma unroll
    for (int m = 0; m < T / 64; ++m) s += mask[b * T + m * 64 + t];
    #pragma unroll
    for (int off = 32; off > 0; off >>= 1) s += __shfl_down(s, off, 64);
    if (t == 0) last[b] = s - 1;
}

// build direction-pure, length-sorted groups of 4 tasks
__global__ void k_plan(const int* __restrict__ last, int* __restrict__ plan,
                       int* __restrict__ slen, int* __restrict__ glen) {
    __shared__ int ll[B];
    const int t = threadIdx.x;   // 128
    ll[t] = last[t];
    __syncthreads();
    const int lf = ll[t] + 1;       // fwd steps
    const int lb = T - ll[t];       // bwd steps
    int rf = 0, rb = 0;
    for (int j = 0; j < B; ++j) {
        const int ljf = ll[j] + 1, ljb = T - ll[j];
        rf += (ljf > lf) || (ljf == lf && j < t);   // descending
        rb += (ljb > lb) || (ljb == lb && j < t);
    }
    plan[rf] = t;       slen[rf] = lf;
    plan[128 + rb] = t; slen[128 + rb] = lb;
    if ((rf & 3) == 0) glen[rf >> 2] = lf;          // rank 4g = group max
    if ((rb & 3) == 0) glen[32 + (rb >> 2)] = lb;
}

// transpose codebook for k_vq
__global__ void k_transpose(float* __restrict__ dst, const float* __restrict__ src,
                            int rows, int cols) {
    const int idx = blockIdx.x * 256 + threadIdx.x;
    const int r = idx % rows;
    const int c = idx / rows;
    dst[idx] = src[r * cols + c];
}

__global__ void k_cbn2(const float* __restrict__ cb, double* __restrict__ cbn2) {
    const int c = blockIdx.x * 256 + threadIdx.x;
    double s = 0.0;
    for (int k = 0; k < D; ++k) {
        const double e = (double)cb[c * D + k];
        s += e * e;
    }
    cbn2[c] = s;
}

// ---------------------------------------------------------------------------
// Cooperative GRU: weights live in VGPRs; 4 WGs per group exchange h slices
// through the LLC with relaxed agent-scope atomics (no fences -> no per-step
// L2 writeback storms). grid = 256 WGs (1/CU, all resident), 768 thr each.
// ---------------------------------------------------------------------------

__device__ __forceinline__ float sigmoidf_(float x) {
    return 1.0f / (1.0f + expf(-x));
}

__global__ __launch_bounds__(NTHR, 3) void k_gru(
    const float* __restrict__ traj,
    const float* __restrict__ Whf, const float* __restrict__ Whb,
    const float* __restrict__ Wxf, const float* __restrict__ Wxb,
    const float* __restrict__ bxf, const float* __restrict__ bhf,
    const float* __restrict__ bxb, const float* __restrict__ bhb,
    const int* __restrict__ plan, const int* __restrict__ slen,
    const int* __restrict__ glen,
    float* __restrict__ hg,        // [2][NG][SEQ][256]
    int* __restrict__ flags,       // [NG][GW*16]
    float* __restrict__ ze)        // [B][512]
{
    const int g   = blockIdx.x & 63;     // same-XCD members under %8 round-robin
    const int w   = blockIdx.x >> 6;
    const int dir = (g >= 32) ? 1 : 0;

    const float* __restrict__ Wh = dir ? Whb : Whf;
    const float* __restrict__ Wx = dir ? Wxb : Wxf;
    const float* __restrict__ bx = dir ? bxb : bxf;
    const float* __restrict__ bh = dir ? bhb : bhf;

    const int tid = threadIdx.x;
    const int q   = tid / ROWS;          // k-chunk 0..3 (wave-uniform)
    const int lr  = tid % ROWS;          // local row 0..191
    const int gi  = lr >> 6;             // gate 0=r,1=z,2=n
    const int jj  = lr & 63;
    const int R   = gi * H + w * 64 + jj;   // global gate-row

    __shared__ float4 h4[SEQ][64];            // full h per sequence (4 KB)
    __shared__ float  Ph[ROWS * 17];          // h-dot partials [row][s*4+q]
    __shared__ float  Px[ROWS * 17];          // x-dot partials
    __shared__ float4 xb4[2][SEQ][8];         // x_t ping-pong
    __shared__ float  lbh[ROWS], lbx[ROWS];
    __shared__ int    bbS[SEQ], lsS[SEQ];

    if (tid < SEQ) { bbS[tid] = plan[g * 4 + tid]; lsS[tid] = slen[g * 4 + tid]; }
    {   // zero h
        float2* hp = (float2*)h4;
        if (tid < 512) hp[tid] = make_float2(0.0f, 0.0f);
    }
    const int L = glen[g];

    // load Wh slice into registers (one-time)
    float4 wh[16];
    {
        const float4* p = (const float4*)(Wh + R * 256 + q * 64);
        #pragma unroll
        for (int i = 0; i < 16; ++i) wh[i] = p[i];
    }
    float4 wx[2];
    {
        const float4* p = (const float4*)(Wx + R * 32 + q * 8);
        wx[0] = p[0]; wx[1] = p[1];
    }
    if (tid < ROWS) { lbh[tid] = bh[R]; lbx[tid] = bx[R]; }
    __syncthreads();
    // x for step 1
    if (tid < 128) {
        const int s = tid >> 5, i = tid & 31;
        const int t0 = dir ? (T - 1) : 0;
        ((float*)xb4)[128 + s * 32 + i] = traj[(bbS[s] * T + t0) * IN + i];
    }
    __syncthreads();

    for (int step = 1; step <= L; ++step) {
        const int buf = step & 1;
        // ---- phase 1: partial dot products (weights in VGPRs) ----
        float a0 = 0.f, a1 = 0.f, a2 = 0.f, a3 = 0.f;
        #pragma unroll
        for (int i = 0; i < 16; ++i) {
            const float4 wv = wh[i];
            float4 hv;
            hv = h4[0][q * 16 + i];
            a0 = fmaf(wv.x, hv.x, fmaf(wv.y, hv.y, fmaf(wv.z, hv.z, fmaf(wv.w, hv.w, a0))));
            hv = h4[1][q * 16 + i];
            a1 = fmaf(wv.x, hv.x, fmaf(wv.y, hv.y, fmaf(wv.z, hv.z, fmaf(wv.w, hv.w, a1))));
            hv = h4[2][q * 16 + i];
            a2 = fmaf(wv.x, hv.x, fmaf(wv.y, hv.y, fmaf(wv.z, hv.z, fmaf(wv.w, hv.w, a2))));
            hv = h4[3][q * 16 + i];
            a3 = fmaf(wv.x, hv.x, fmaf(wv.y, hv.y, fmaf(wv.z, hv.z, fmaf(wv.w, hv.w, a3))));
        }
        float b0 = 0.f, b1 = 0.f, b2 = 0.f, b3 = 0.f;
        #pragma unroll
        for (int i = 0; i < 2; ++i) {
            const float4 wv = wx[i];
            float4 xv;
            xv = xb4[buf][0][q * 2 + i];
            b0 = fmaf(wv.x, xv.x, fmaf(wv.y, xv.y, fmaf(wv.z, xv.z, fmaf(wv.w, xv.w, b0))));
            xv = xb4[buf][1][q * 2 + i];
            b1 = fmaf(wv.x, xv.x, fmaf(wv.y, xv.y, fmaf(wv.z, xv.z, fmaf(wv.w, xv.w, b1))));
            xv = xb4[buf][2][q * 2 + i];
            b2 = fmaf(wv.x, xv.x, fmaf(wv.y, xv.y, fmaf(wv.z, xv.z, fmaf(wv.w, xv.w, b2))));
            xv = xb4[buf][3][q * 2 + i];
            b3 = fmaf(wv.x, xv.x, fmaf(wv.y, xv.y, fmaf(wv.z, xv.z, fmaf(wv.w, xv.w, b3))));
        }
        {
            const int o = lr * 17 + q;
            Ph[o]      = a0; Ph[o + 4]  = a1; Ph[o + 8]  = a2; Ph[o + 12] = a3;
            Px[o]      = b0; Px[o + 4]  = b1; Px[o + 8]  = b2; Px[o + 12] = b3;
        }
        __syncthreads();

        // ---- phase 2: combine gates (256 thr) + x prefetch (128 thr) ----
        if (tid < 256) {
            const int j2 = tid & 63, s = tid >> 6;
            const int c = s * 4;
            float hr = 0.f, hz = 0.f, hn_ = 0.f, xr = 0.f, xz = 0.f, xn = 0.f;
            #pragma unroll
            for (int q2 = 0; q2 < 4; ++q2) {
                hr  += Ph[j2 * 17 + c + q2];
                hz  += Ph[(64 + j2) * 17 + c + q2];
                hn_ += Ph[(128 + j2) * 17 + c + q2];
                xr  += Px[j2 * 17 + c + q2];
                xz  += Px[(64 + j2) * 17 + c + q2];
                xn  += Px[(128 + j2) * 17 + c + q2];
            }
            const float r = sigmoidf_(xr + lbx[j2] + hr + lbh[j2]);
            const float z = sigmoidf_(xz + lbx[64 + j2] + hz + lbh[64 + j2]);
            const float n = tanhf(xn + lbx[128 + j2] + r * (hn_ + lbh[128 + j2]));
            const int jg = w * 64 + j2;
            const float hp = ((const float*)h4)[s * 256 + jg];
            const float hnew = (1.0f - z) * n + z * hp;
            // communicated bytes go through LLC-coherent (agent-scope) stores:
            __hip_atomic_store(&hg[buf * (NG * SEQ * 256) + g * (SEQ * 256)
                                   + s * 256 + jg],
                               hnew, __ATOMIC_RELAXED, __HIP_MEMORY_SCOPE_AGENT);
            if (step == lsS[s]) ze[bbS[s] * D + dir * H + jg] = hnew;
        } else if (tid < 384) {
            if (step < L) {
                const int u = tid - 256;
                const int s = u >> 5, i = u & 31;
                const int tn = dir ? (T - 1 - step) : step;
                ((float*)xb4)[(buf ^ 1) * 128 + s * 32 + i] =
                    traj[(bbS[s] * T + tn) * IN + i];
            }
        }
        __syncthreads();   // s_waitcnt vmcnt(0) before barrier: slice stores done

        // ---- inter-WG sync: relaxed agent atomics only (NO fences) ----
        if (tid == 0) {
            __hip_atomic_store(&flags[g * 64 + w * 16], step,
                               __ATOMIC_RELAXED, __HIP_MEMORY_SCOPE_AGENT);
        }
        if (tid < GW) {
            while (__hip_atomic_load(&flags[g * 64 + tid * 16],
                                     __ATOMIC_RELAXED, __HIP_MEMORY_SCOPE_AGENT) < step) {
                __builtin_amdgcn_s_sleep(1);
            }
        }
        __syncthreads();

        // ---- gather full h for next step (64-bit agent-scope loads) ----
        if (tid < 512) {
            const unsigned long long* src =
                (const unsigned long long*)(hg + buf * (NG * SEQ * 256)
                                               + g * (SEQ * 256));
            const unsigned long long v =
                __hip_atomic_load(&src[tid], __ATOMIC_RELAXED,
                                  __HIP_MEMORY_SCOPE_AGENT);
            ((unsigned long long*)h4)[tid] = v;
        }
        __syncthreads();
    }
}

// ---------------------------------------------------------------------------
// VQ: fp64 distance accumulation to match the numpy (fp64) argmin ordering.
// ---------------------------------------------------------------------------

__global__ __launch_bounds__(256) void k_vq(
    const float* __restrict__ ze, const float* __restrict__ cbT,
    const float* __restrict__ cb, const double* __restrict__ cbn2,
    int* __restrict__ counts, double* __restrict__ lsum,
    float* __restrict__ out)
{
    __shared__ float lz[D];
    __shared__ double ds[256];
    __shared__ int cs[256];

    const int b = blockIdx.x;
    const int t = threadIdx.x;

    lz[t]       = ze[b * D + t];
    lz[t + 256] = ze[b * D + 256 + t];
    __syncthreads();

    double best = 1e300;
    int bc = 0;
    for (int m = 0; m < NC / 256; ++m) {
        const int c = m * 256 + t;
        double s2 = 0.0;
        #pragma unroll 4
        for (int k = 0; k < D; ++k)
            s2 += (double)lz[k] * (double)cbT[k * NC + c];
        const double dist = cbn2[c] - 2.0 * s2;
        if (dist < best) { best = dist; bc = c; }
    }
    ds[t] = best; cs[t] = bc;
    __syncthreads();
    for (int s = 128; s > 0; s >>= 1) {
        if (t < s) {
            if (ds[t + s] < ds[t] || (ds[t + s] == ds[t] && cs[t + s] < cs[t])) {
                ds[t] = ds[t + s]; cs[t] = cs[t + s];
            }
        }
        __syncthreads();
    }
    const int idx = cs[0];
    __syncthreads();

    if (t == 0) atomicAdd(&counts[idx], 1);

    double loc = 0.0;
    for (int jj = t; jj < D; jj += 256) {
        const float zev = lz[jj];
        const float zqv = cb[idx * D + jj];
        out[b * D + jj] = zev + (zqv - zev);
        const double df = (double)zqv - (double)zev;
        loc += df * df;
    }
    ds[t] = loc;
    __syncthreads();
    for (int s = 128; s > 0; s >>= 1) {
        if (t < s) ds[t] += ds[t + s];
        __syncthreads();
    }
    if (t == 0) atomicAdd(lsum, ds[0]);
}

__global__ void k_final(const int* __restrict__ counts,
                        const double* __restrict__ lsum,
                        float* __restrict__ out)
{
    __shared__ double ds[256];
    const int t = threadIdx.x;
    double s = 0.0;
    for (int c = t; c < NC; c += 256) {
        const double p = (double)counts[c] / (double)B;
        s += p * log(p + 1e-10);
    }
    ds[t] = s;
    __syncthreads();
    for (int r = 128; r > 0; r >>= 1) {
        if (t < r) ds[t] += ds[t + r];
        __syncthreads();
    }
    if (t == 0) {
        out[B * D]     = (float)(lsum[0] * 1.25 / (double)(B * D));
        out[B * D + 1] = (float)exp(-ds[0]);
    }
}

// ---------------------------------------------------------------------------
// launch
// ---------------------------------------------------------------------------

extern "C" void kernel_launch(void* const* d_in, const int* in_sizes, int n_in,
                              void* d_out, int out_size, void* d_ws, size_t ws_size,
                              hipStream_t stream) {
    const float* traj = (const float*)d_in[0];
    const int*   mask = (const int*)d_in[1];
    const float* Wxf  = (const float*)d_in[2];
    const float* Whf  = (const float*)d_in[3];
    const float* bxf  = (const float*)d_in[4];
    const float* bhf  = (const float*)d_in[5];
    const float* Wxb  = (const float*)d_in[6];
    const float* Whb  = (const float*)d_in[7];
    const float* bxb  = (const float*)d_in[8];
    const float* bhb  = (const float*)d_in[9];
    const float* cb   = (const float*)d_in[10];
    float* out = (float*)d_out;

    // workspace layout
    float* ws    = (float*)d_ws;
    float* cbT   = ws;                     // 512*1024 = 524288
    float* zebuf = cbT + 524288;           // 128*512  = 65536
    float* hg    = zebuf + 65536;          // 2*64*4*256 = 131072
    int*   last  = (int*)(hg + 131072);    // 128
    int*   plan  = last + 128;             // 256
    int*   slen  = plan + 256;             // 256
    int*   glen  = slen + 256;             // 64
    int*   flags = glen + 64;              // 64*64 = 4096
    int*   cnts  = flags + 4096;           // 1024
    double* cbn2 = (double*)(cnts + 1024); // 1024 doubles (8B aligned)
    double* lsum = cbn2 + 1024;            // 1 double

    k_zero<<<dim3(16), dim3(256), 0, stream>>>(flags, cnts, lsum);
    k_lengths<<<dim3(B), dim3(64), 0, stream>>>(mask, last);
    k_plan<<<dim3(1), dim3(B), 0, stream>>>(last, plan, slen, glen);

    k_transpose<<<dim3(2048), dim3(256), 0, stream>>>(cbT, cb, NC, D);
    k_cbn2<<<dim3(4), dim3(256), 0, stream>>>(cb, cbn2);

    k_gru<<<dim3(NG * GW), dim3(NTHR), 0, stream>>>(
        traj, Whf, Whb, Wxf, Wxb, bxf, bhf, bxb, bhb,
        plan, slen, glen, hg, flags, zebuf);

    k_vq<<<dim3(B), dim3(256), 0, stream>>>(zebuf, cbT, cb, cbn2, cnts, lsum, out);
    k_final<<<dim3(1), dim3(256), 0, stream>>>(cnts, lsum, out);
}

// Round 4
// 1977.135 us; speedup vs baseline: 3.2525x; 1.2002x over previous
//
#include <hip/hip_runtime.h>
#include <math.h>

// Problem constants
constexpr int B  = 128;
constexpr int T  = 512;
constexpr int IN = 32;
constexpr int H  = 256;
constexpr int D  = 2 * H;     // 512
constexpr int NC = 1024;      // codebook entries

// cooperative GRU geometry
constexpr int NG   = 64;      // groups (32 fwd + 32 bwd)
constexpr int GW   = 4;       // WGs per group
constexpr int SEQ  = 4;       // sequences per group
constexpr int ROWS = 192;     // gate-rows per WG (3 gates x 64 j)
constexpr int NTHR = 768;     // ROWS x 4 k-chunks

// ---------------------------------------------------------------------------
// prep kernels
// ---------------------------------------------------------------------------

__global__ void k_zero(int* __restrict__ counts, double* __restrict__ lsum) {
    const int i = blockIdx.x * 256 + threadIdx.x;
    if (i < NC) counts[i] = 0;
    if (i == 0) *lsum = 0.0;
}

__global__ void k_lengths(const int* __restrict__ mask, int* __restrict__ last) {
    const int b = blockIdx.x;
    const int t = threadIdx.x;   // 64 threads = 1 wave
    int s = 0;
    #pragma unroll
    for (int m = 0; m < T / 64; ++m) s += mask[b * T + m * 64 + t];
    #pragma unroll
    for (int off = 32; off > 0; off >>= 1) s += __shfl_down(s, off, 64);
    if (t == 0) last[b] = s - 1;
}

// build direction-pure, length-sorted groups of 4 tasks
__global__ void k_plan(const int* __restrict__ last, int* __restrict__ plan,
                       int* __restrict__ slen, int* __restrict__ glen) {
    __shared__ int ll[B];
    const int t = threadIdx.x;   // 128
    ll[t] = last[t];
    __syncthreads();
    const int lf = ll[t] + 1;       // fwd steps
    const int lb = T - ll[t];       // bwd steps
    int rf = 0, rb = 0;
    for (int j = 0; j < B; ++j) {
        const int ljf = ll[j] + 1, ljb = T - ll[j];
        rf += (ljf > lf) || (ljf == lf && j < t);   // descending
        rb += (ljb > lb) || (ljb == lb && j < t);
    }
    plan[rf] = t;       slen[rf] = lf;
    plan[128 + rb] = t; slen[128 + rb] = lb;
    if ((rf & 3) == 0) glen[rf >> 2] = lf;          // rank 4g = group max
    if ((rb & 3) == 0) glen[32 + (rb >> 2)] = lb;
}

// transpose codebook for k_vq
__global__ void k_transpose(float* __restrict__ dst, const float* __restrict__ src,
                            int rows, int cols) {
    const int idx = blockIdx.x * 256 + threadIdx.x;
    const int r = idx % rows;
    const int c = idx / rows;
    dst[idx] = src[r * cols + c];
}

__global__ void k_cbn2(const float* __restrict__ cb, double* __restrict__ cbn2) {
    const int c = blockIdx.x * 256 + threadIdx.x;
    double s = 0.0;
    for (int k = 0; k < D; ++k) {
        const double e = (double)cb[c * D + k];
        s += e * e;
    }
    cbn2[c] = s;
}

// ---------------------------------------------------------------------------
// Cooperative GRU: weights in VGPRs; 4 WGs per group exchange h as
// step-TAGGED 8B atomic words through the LLC. Readers spin on the data
// itself (no flags, no fences). Gather overlaps local gate math.
// ---------------------------------------------------------------------------

__device__ __forceinline__ float sigmoidf_(float x) {
    return 1.0f / (1.0f + expf(-x));
}

__global__ __launch_bounds__(NTHR, 3) void k_gru(
    const float* __restrict__ traj,
    const float* __restrict__ Whf, const float* __restrict__ Whb,
    const float* __restrict__ Wxf, const float* __restrict__ Wxb,
    const float* __restrict__ bxf, const float* __restrict__ bhf,
    const float* __restrict__ bxb, const float* __restrict__ bhb,
    const int* __restrict__ plan, const int* __restrict__ slen,
    const int* __restrict__ glen,
    unsigned long long* __restrict__ hgt,  // [2][NG][GW][SEQ*64] tagged pairs
    float* __restrict__ ze)                // [B][512]
{
    const int g   = blockIdx.x & 63;     // same-XCD members under %8 round-robin
    const int w   = blockIdx.x >> 6;
    const int dir = (g >= 32) ? 1 : 0;

    const float* __restrict__ Wh = dir ? Whb : Whf;
    const float* __restrict__ Wx = dir ? Wxb : Wxf;
    const float* __restrict__ bx = dir ? bxb : bxf;
    const float* __restrict__ bh = dir ? bhb : bhf;

    const int tid = threadIdx.x;
    const int q   = tid / ROWS;          // k-chunk 0..3 (wave-uniform)
    const int lr  = tid % ROWS;          // local row 0..191
    const int gi  = lr >> 6;             // gate 0=r,1=z,2=n
    const int jj  = lr & 63;
    const int R   = gi * H + w * 64 + jj;   // global gate-row

    __shared__ float4 h4[SEQ][64];            // full h per sequence (4 KB)
    __shared__ float  Ph[ROWS * 17];          // h-dot partials [row][s*4+q]
    __shared__ float  Px[ROWS * 17];          // x-dot partials
    __shared__ float4 xb4[2][SEQ][8];         // x_t ping-pong
    __shared__ float  lbh[ROWS], lbx[ROWS];
    __shared__ int    bbS[SEQ], lsS[SEQ];

    if (tid < SEQ) { bbS[tid] = plan[g * 4 + tid]; lsS[tid] = slen[g * 4 + tid]; }
    {   // zero h
        float2* hp = (float2*)h4;
        if (tid < 512) hp[tid] = make_float2(0.0f, 0.0f);
    }
    const int L = glen[g];

    // load Wh slice into registers (one-time)
    float4 wh[16];
    {
        const float4* p = (const float4*)(Wh + R * 256 + q * 64);
        #pragma unroll
        for (int i = 0; i < 16; ++i) wh[i] = p[i];
    }
    float4 wx[2];
    {
        const float4* p = (const float4*)(Wx + R * 32 + q * 8);
        wx[0] = p[0]; wx[1] = p[1];
    }
    if (tid < ROWS) { lbh[tid] = bh[R]; lbx[tid] = bx[R]; }
    __syncthreads();
    // x for step 1
    if (tid < 128) {
        const int s = tid >> 5, i = tid & 31;
        const int t0 = dir ? (T - 1) : 0;
        ((float*)xb4)[128 + s * 32 + i] = traj[(bbS[s] * T + t0) * IN + i];
    }
    __syncthreads();

    // gather-role constants (tid 256..767 handle the 3 peers' 768 pairs)
    const int u = tid - 256;                     // 0..511 for gather threads

    for (int step = 1; step <= L; ++step) {
        const int buf = step & 1;
        unsigned long long* __restrict__ slab =
            hgt + (buf * NG + g) * (GW * SEQ * 64);

        // ---- phase 1: partial dot products (weights in VGPRs) ----
        float4 a0 = {0,0,0,0}, a1 = {0,0,0,0}, a2 = {0,0,0,0}, a3 = {0,0,0,0};
        #pragma unroll
        for (int i = 0; i < 16; ++i) {
            const float4 wv = wh[i];
            float4 hv;
            hv = h4[0][q * 16 + i];
            a0.x = fmaf(wv.x, hv.x, a0.x); a0.y = fmaf(wv.y, hv.y, a0.y);
            a0.z = fmaf(wv.z, hv.z, a0.z); a0.w = fmaf(wv.w, hv.w, a0.w);
            hv = h4[1][q * 16 + i];
            a1.x = fmaf(wv.x, hv.x, a1.x); a1.y = fmaf(wv.y, hv.y, a1.y);
            a1.z = fmaf(wv.z, hv.z, a1.z); a1.w = fmaf(wv.w, hv.w, a1.w);
            hv = h4[2][q * 16 + i];
            a2.x = fmaf(wv.x, hv.x, a2.x); a2.y = fmaf(wv.y, hv.y, a2.y);
            a2.z = fmaf(wv.z, hv.z, a2.z); a2.w = fmaf(wv.w, hv.w, a2.w);
            hv = h4[3][q * 16 + i];
            a3.x = fmaf(wv.x, hv.x, a3.x); a3.y = fmaf(wv.y, hv.y, a3.y);
            a3.z = fmaf(wv.z, hv.z, a3.z); a3.w = fmaf(wv.w, hv.w, a3.w);
        }
        float b0 = 0.f, b1 = 0.f, b2 = 0.f, b3 = 0.f;
        #pragma unroll
        for (int i = 0; i < 2; ++i) {
            const float4 wv = wx[i];
            float4 xv;
            xv = xb4[buf][0][q * 2 + i];
            b0 = fmaf(wv.x, xv.x, fmaf(wv.y, xv.y, fmaf(wv.z, xv.z, fmaf(wv.w, xv.w, b0))));
            xv = xb4[buf][1][q * 2 + i];
            b1 = fmaf(wv.x, xv.x, fmaf(wv.y, xv.y, fmaf(wv.z, xv.z, fmaf(wv.w, xv.w, b1))));
            xv = xb4[buf][2][q * 2 + i];
            b2 = fmaf(wv.x, xv.x, fmaf(wv.y, xv.y, fmaf(wv.z, xv.z, fmaf(wv.w, xv.w, b2))));
            xv = xb4[buf][3][q * 2 + i];
            b3 = fmaf(wv.x, xv.x, fmaf(wv.y, xv.y, fmaf(wv.z, xv.z, fmaf(wv.w, xv.w, b3))));
        }
        {
            const int o = lr * 17 + q;
            Ph[o]      = a0.x + a0.y + a0.z + a0.w;
            Ph[o + 4]  = a1.x + a1.y + a1.z + a1.w;
            Ph[o + 8]  = a2.x + a2.y + a2.z + a2.w;
            Ph[o + 12] = a3.x + a3.y + a3.z + a3.w;
            Px[o]      = b0; Px[o + 4]  = b1; Px[o + 8]  = b2; Px[o + 12] = b3;
        }
        __syncthreads();

        // ---- phase 2 (tid<256): combine gates, publish tagged pairs ----
        //      (tid>=256): spin-gather peers' tagged h + x prefetch
        if (tid < 256) {
            const int j2 = tid & 63, s = tid >> 6;
            const int c = s * 4;
            float hr = 0.f, hz = 0.f, hn_ = 0.f, xr = 0.f, xz = 0.f, xn = 0.f;
            #pragma unroll
            for (int q2 = 0; q2 < 4; ++q2) {
                hr  += Ph[j2 * 17 + c + q2];
                hz  += Ph[(64 + j2) * 17 + c + q2];
                hn_ += Ph[(128 + j2) * 17 + c + q2];
                xr  += Px[j2 * 17 + c + q2];
                xz  += Px[(64 + j2) * 17 + c + q2];
                xn  += Px[(128 + j2) * 17 + c + q2];
            }
            const float r = sigmoidf_(xr + lbx[j2] + hr + lbh[j2]);
            const float z = sigmoidf_(xz + lbx[64 + j2] + hz + lbh[64 + j2]);
            const float n = tanhf(xn + lbx[128 + j2] + r * (hn_ + lbh[128 + j2]));
            const int jg = w * 64 + j2;
            const float hp = ((const float*)h4)[s * 256 + jg];
            const float hnew = (1.0f - z) * n + z * hp;
            // own slice locally into LDS (phase-1 done reading: barrier passed)
            ((float*)h4)[s * 256 + jg] = hnew;
            // publish tagged pair for peers
            union { float f; unsigned ui; } cv; cv.f = hnew;
            const unsigned long long pk =
                ((unsigned long long)(unsigned)step << 32) | cv.ui;
            __hip_atomic_store(&slab[w * 256 + s * 64 + j2], pk,
                               __ATOMIC_RELAXED, __HIP_MEMORY_SCOPE_AGENT);
            if (step == lsS[s]) ze[bbS[s] * D + dir * H + jg] = hnew;
        } else {
            // x prefetch (issue early; completes during spins)
            float xval = 0.0f;
            int xs = 0, xi = 0;
            const bool do_x = (u < 128) && (step < L);
            if (do_x) {
                xs = u >> 5; xi = u & 31;
                const int tn = dir ? (T - 1 - step) : step;
                xval = traj[(bbS[xs] * T + tn) * IN + xi];
            }
            // pair 0: flat f = u  (peers list index 0..1)
            {
                const int p_idx = u >> 8;            // 0 or 1
                const int r2 = u & 255;
                const int s = r2 >> 6, j = r2 & 63;
                const int pw = p_idx + (p_idx >= w ? 1 : 0);
                unsigned long long v;
                do {
                    v = __hip_atomic_load(&slab[pw * 256 + s * 64 + j],
                                          __ATOMIC_RELAXED, __HIP_MEMORY_SCOPE_AGENT);
                } while ((int)(v >> 32) < step);
                union { unsigned ui; float f; } cv; cv.ui = (unsigned)v;
                ((float*)h4)[s * 256 + pw * 64 + j] = cv.f;
            }
            // pair 1 (u<256): flat f = u + 512 (peers list index 2)
            if (u < 256) {
                const int s = u >> 6, j = u & 63;
                const int pw = 2 + (2 >= w ? 1 : 0);
                unsigned long long v;
                do {
                    v = __hip_atomic_load(&slab[pw * 256 + s * 64 + j],
                                          __ATOMIC_RELAXED, __HIP_MEMORY_SCOPE_AGENT);
                } while ((int)(v >> 32) < step);
                union { unsigned ui; float f; } cv; cv.ui = (unsigned)v;
                ((float*)h4)[s * 256 + pw * 64 + j] = cv.f;
            }
            if (do_x)
                ((float*)xb4)[(buf ^ 1) * 128 + xs * 32 + xi] = xval;
        }
        __syncthreads();
    }
}

// ---------------------------------------------------------------------------
// VQ: fp64 distance accumulation to match the numpy (fp64) argmin ordering.
// ---------------------------------------------------------------------------

__global__ __launch_bounds__(256) void k_vq(
    const float* __restrict__ ze, const float* __restrict__ cbT,
    const float* __restrict__ cb, const double* __restrict__ cbn2,
    int* __restrict__ counts, double* __restrict__ lsum,
    float* __restrict__ out)
{
    __shared__ float lz[D];
    __shared__ double ds[256];
    __shared__ int cs[256];

    const int b = blockIdx.x;
    const int t = threadIdx.x;

    lz[t]       = ze[b * D + t];
    lz[t + 256] = ze[b * D + 256 + t];
    __syncthreads();

    double best = 1e300;
    int bc = 0;
    for (int m = 0; m < NC / 256; ++m) {
        const int c = m * 256 + t;
        double s2 = 0.0;
        #pragma unroll 4
        for (int k = 0; k < D; ++k)
            s2 += (double)lz[k] * (double)cbT[k * NC + c];
        const double dist = cbn2[c] - 2.0 * s2;
        if (dist < best) { best = dist; bc = c; }
    }
    ds[t] = best; cs[t] = bc;
    __syncthreads();
    for (int s = 128; s > 0; s >>= 1) {
        if (t < s) {
            if (ds[t + s] < ds[t] || (ds[t + s] == ds[t] && cs[t + s] < cs[t])) {
                ds[t] = ds[t + s]; cs[t] = cs[t + s];
            }
        }
        __syncthreads();
    }
    const int idx = cs[0];
    __syncthreads();

    if (t == 0) atomicAdd(&counts[idx], 1);

    double loc = 0.0;
    for (int jj = t; jj < D; jj += 256) {
        const float zev = lz[jj];
        const float zqv = cb[idx * D + jj];
        out[b * D + jj] = zev + (zqv - zev);
        const double df = (double)zqv - (double)zev;
        loc += df * df;
    }
    ds[t] = loc;
    __syncthreads();
    for (int s = 128; s > 0; s >>= 1) {
        if (t < s) ds[t] += ds[t + s];
        __syncthreads();
    }
    if (t == 0) atomicAdd(lsum, ds[0]);
}

__global__ void k_final(const int* __restrict__ counts,
                        const double* __restrict__ lsum,
                        float* __restrict__ out)
{
    __shared__ double ds[256];
    const int t = threadIdx.x;
    double s = 0.0;
    for (int c = t; c < NC; c += 256) {
        const double p = (double)counts[c] / (double)B;
        s += p * log(p + 1e-10);
    }
    ds[t] = s;
    __syncthreads();
    for (int r = 128; r > 0; r >>= 1) {
        if (t < r) ds[t] += ds[t + r];
        __syncthreads();
    }
    if (t == 0) {
        out[B * D]     = (float)(lsum[0] * 1.25 / (double)(B * D));
        out[B * D + 1] = (float)exp(-ds[0]);
    }
}

// ---------------------------------------------------------------------------
// launch
// ---------------------------------------------------------------------------

extern "C" void kernel_launch(void* const* d_in, const int* in_sizes, int n_in,
                              void* d_out, int out_size, void* d_ws, size_t ws_size,
                              hipStream_t stream) {
    const float* traj = (const float*)d_in[0];
    const int*   mask = (const int*)d_in[1];
    const float* Wxf  = (const float*)d_in[2];
    const float* Whf  = (const float*)d_in[3];
    const float* bxf  = (const float*)d_in[4];
    const float* bhf  = (const float*)d_in[5];
    const float* Wxb  = (const float*)d_in[6];
    const float* Whb  = (const float*)d_in[7];
    const float* bxb  = (const float*)d_in[8];
    const float* bhb  = (const float*)d_in[9];
    const float* cb   = (const float*)d_in[10];
    float* out = (float*)d_out;

    // workspace layout
    float* ws    = (float*)d_ws;
    float* cbT   = ws;                     // 512*1024 = 524288 floats
    float* zebuf = cbT + 524288;           // 128*512  = 65536
    unsigned long long* hgt =
        (unsigned long long*)(zebuf + 65536);   // 2*64*4*256 u64 = 131072 (1 MB)
    int*   last  = (int*)(hgt + 131072);   // 128
    int*   plan  = last + 128;             // 256
    int*   slen  = plan + 256;             // 256
    int*   glen  = slen + 256;             // 64
    int*   cnts  = glen + 64;              // 1024
    double* cbn2 = (double*)(cnts + 1024 + 4); // 1024 doubles (8B aligned)
    double* lsum = cbn2 + 1024;            // 1 double

    k_zero<<<dim3(4), dim3(256), 0, stream>>>(cnts, lsum);
    k_lengths<<<dim3(B), dim3(64), 0, stream>>>(mask, last);
    k_plan<<<dim3(1), dim3(B), 0, stream>>>(last, plan, slen, glen);

    k_transpose<<<dim3(2048), dim3(256), 0, stream>>>(cbT, cb, NC, D);
    k_cbn2<<<dim3(4), dim3(256), 0, stream>>>(cb, cbn2);

    k_gru<<<dim3(NG * GW), dim3(NTHR), 0, stream>>>(
        traj, Whf, Whb, Wxf, Wxb, bxf, bhf, bxb, bhb,
        plan, slen, glen, hgt, zebuf);

    k_vq<<<dim3(B), dim3(256), 0, stream>>>(zebuf, cbT, cb, cbn2, cnts, lsum, out);
    k_final<<<dim3(1), dim3(256), 0, stream>>>(cnts, lsum, out);
}